// Round 7
// baseline (152.810 us; speedup 1.0000x reference)
//
#include <hip/hip_runtime.h>
#include <math.h>
#include <stdint.h>

// NetVLAD: N=32, C=512, P=1024, K=64, ALPHA=100. Split-bf16 MFMA.
// R14: STRUCTURAL FUSION. assign+vlad -> one kernel (grid 256 = (n, 8
// p-tiles of 128)): R13 assign pipeline verbatim -> softmax -> a2 kept in
// LDS (aT never hits HBM) -> vlad MFMA for this p-tile (x re-read L2-hot)
// -> f32 partials[n][pt][k][c] to ws. combine kernel (32 blocks) sums 8
// partials, -asum*v, intra+global norms, writes out (absorbs scale).
// Rationale: 4 falsified micro-theories; assign pinned at 40-50us across
// all structures at ~800GB/s effective; remaining levers = fewer bytes
// (aT round-trip, 2nd x read) + fewer serialization points (4->3
// dispatches, no global barrier between assign and vlad phases).
#define ALPHA 100.0f
#define EPSN 1e-12f

typedef __attribute__((ext_vector_type(8))) short bf16x8;
typedef __attribute__((ext_vector_type(16))) float f32x16;
typedef __attribute__((ext_vector_type(4))) float f32x4;
typedef __attribute__((ext_vector_type(4))) unsigned int u32x4;

static __device__ __forceinline__ uint32_t f2bf(float f) {
    uint32_t u = __builtin_bit_cast(uint32_t, f);
    return (u + 0x7FFFu + ((u >> 16) & 1u)) >> 16;  // RNE
}
static __device__ __forceinline__ float bfhi(uint32_t u) {
    return __builtin_bit_cast(float, u & 0xFFFF0000u);
}
static __device__ __forceinline__ uint32_t packbf(float a, float b) {
    return f2bf(a) | (f2bf(b) << 16);
}
static __device__ __forceinline__ void lds_barrier() {
    asm volatile("s_waitcnt lgkmcnt(0)\n\ts_barrier" ::: "memory");
}

// ------- prep: v -> (vh, vl) bf16 split [k][c]; bias[k]; zero asum ---------
__global__ __launch_bounds__(64) void prep_kernel(const float* __restrict__ v,
                                                  unsigned short* __restrict__ vh,
                                                  unsigned short* __restrict__ vl,
                                                  float* __restrict__ bias,
                                                  float* __restrict__ az) {
    int k = blockIdx.x, lane = threadIdx.x;
    az[k * 64 + lane] = 0.f;  // zero asum region (2048 used)
    const float* row = v + k * 512;
    float ssq = 0.f;
#pragma unroll
    for (int i = 0; i < 8; ++i) {
        int c = lane + 64 * i;
        float f = row[c];
        ssq = fmaf(f, f, ssq);
        uint32_t hi = f2bf(f);
        uint32_t lo = f2bf(f - __builtin_bit_cast(float, hi << 16));
        vh[k * 512 + c] = (unsigned short)hi;
        vl[k * 512 + c] = (unsigned short)lo;
    }
#pragma unroll
    for (int off = 32; off > 0; off >>= 1) ssq += __shfl_xor(ssq, off, 64);
    if (lane == 0) bias[k] = -ALPHA * sqrtf(ssq);
}

// ============ fused: assign (R13 pipeline) + softmax + vlad partial ========
// grid 256 = (n, 128-p tile); block 512 = 8 waves: (kh, ps).
// assign phase: ps = p-quarter. vlad phase: ps = c-quarter (cq).
__global__ __launch_bounds__(512) void fused_kernel(
    const float* __restrict__ x, const unsigned short* __restrict__ vh,
    const unsigned short* __restrict__ vl, const float* __restrict__ bias,
    float* __restrict__ pw, float* __restrict__ asum) {
    __shared__ uint32_t xsh[2][16 * 132];  // assign: [dbuf][c-pair][128p +pad]
    __shared__ uint32_t xsl[2][16 * 132];
    __shared__ float ssq_s[16][132];
    __shared__ float ssq_l[128];
    __shared__ float bias_l[64];
    __shared__ float xchm[4][2][32];
    __shared__ float xchs[4][2][32];
    __shared__ float a2f[64 * 132];        // vlad: a2 f32 [k][128p +pad]
    __shared__ uint32_t xv[128 * 68];      // vlad: x bf16-pairs [c-sub rows][64pp +pad]

    int tid = threadIdx.x, bx = blockIdx.x;
    int n = bx >> 3, pt = bx & 7, pblk = pt << 7;
    int l = tid & 63, w = tid >> 6;
    int kh = w & 1, ps = w >> 1;  // ps in 0..3
    int h = l >> 5, cl = l & 31;
    int r = tid >> 5, q = tid & 31;  // assign staging: c-pair r, p-quad q

    if (tid < 64) bias_l[tid] = bias[tid];

    const float* xg = x + (size_t)n * 524288 + (size_t)(2 * r) * 1024 + pblk + 4 * q;
    const unsigned short* vhg = vh + (size_t)(32 * kh + cl) * 512 + 8 * h;
    const unsigned short* vlg = vl + (size_t)(32 * kh + cl) * 512 + 8 * h;

    f32x16 accA, accB;
#pragma unroll
    for (int i = 0; i < 16; ++i) { accA[i] = 0.f; accB[i] = 0.f; }
    f32x4 ssqv;
#pragma unroll
    for (int i = 0; i < 4; ++i) ssqv[i] = 0.f;

    float4 xa[3], xb[3];
    u32x4 vfh[3][2], vfl[3][2];

#define A_LOAD(slot, cc)                                                       \
    do {                                                                       \
        xa[slot] = *(const float4*)(xg + (size_t)(cc)*32768);                  \
        xb[slot] = *(const float4*)(xg + (size_t)(cc)*32768 + 1024);           \
        vfh[slot][0] = *(const u32x4*)(vhg + (cc)*32);                         \
        vfh[slot][1] = *(const u32x4*)(vhg + (cc)*32 + 16);                    \
        vfl[slot][0] = *(const u32x4*)(vlg + (cc)*32);                         \
        vfl[slot][1] = *(const u32x4*)(vlg + (cc)*32 + 16);                    \
    } while (0)
#define A_STAGE(buf, slot)                                                     \
    do {                                                                       \
        float fa[4] = {xa[slot].x, xa[slot].y, xa[slot].z, xa[slot].w};        \
        float fb[4] = {xb[slot].x, xb[slot].y, xb[slot].z, xb[slot].w};        \
        u32x4 hp, lp;                                                          \
        _Pragma("unroll") for (int i = 0; i < 4; ++i) {                        \
            uint32_t h0 = f2bf(fa[i]);                                         \
            uint32_t l0 = f2bf(fa[i] - bfhi(h0 << 16));                        \
            uint32_t h1 = f2bf(fb[i]);                                         \
            uint32_t l1 = f2bf(fb[i] - bfhi(h1 << 16));                        \
            hp[i] = h0 | (h1 << 16);                                           \
            lp[i] = l0 | (l1 << 16);                                           \
            ssqv[i] = fmaf(fa[i], fa[i], fmaf(fb[i], fb[i], ssqv[i]));         \
        }                                                                      \
        *(u32x4*)&xsh[buf][r * 132 + 4 * q] = hp;                              \
        *(u32x4*)&xsl[buf][r * 132 + 4 * q] = lp;                              \
    } while (0)
#define A_COMPUTE(buf, slot)                                                   \
    do {                                                                       \
        _Pragma("unroll") for (int s = 0; s < 2; ++s) {                        \
            int xb_ = (8 * s + 4 * h) * 132 + 32 * ps + cl;                    \
            u32x4 bhp, blp;                                                    \
            _Pragma("unroll") for (int q2 = 0; q2 < 4; ++q2) {                 \
                bhp[q2] = xsh[buf][xb_ + q2 * 132];                            \
                blp[q2] = xsl[buf][xb_ + q2 * 132];                            \
            }                                                                  \
            bf16x8 ah = __builtin_bit_cast(bf16x8, vfh[slot][s]);              \
            bf16x8 al = __builtin_bit_cast(bf16x8, vfl[slot][s]);              \
            bf16x8 xh_ = __builtin_bit_cast(bf16x8, bhp);                      \
            bf16x8 xl_ = __builtin_bit_cast(bf16x8, blp);                      \
            f32x16& accr = s ? accB : accA;                                    \
            accr = __builtin_amdgcn_mfma_f32_32x32x16_bf16(ah, xh_, accr, 0, 0, 0);\
            accr = __builtin_amdgcn_mfma_f32_32x32x16_bf16(ah, xl_, accr, 0, 0, 0);\
            accr = __builtin_amdgcn_mfma_f32_32x32x16_bf16(al, xh_, accr, 0, 0, 0);\
        }                                                                      \
    } while (0)

    A_LOAD(0, 0);
    A_LOAD(1, 1);
    A_LOAD(2, 2);
    A_STAGE(0, 0);
    lds_barrier();
#pragma unroll
    for (int cc = 0; cc < 16; ++cc) {
        if (cc < 15) A_STAGE((cc + 1) & 1, (cc + 1) % 3);
        A_COMPUTE(cc & 1, cc % 3);
        if (cc < 13) A_LOAD(cc % 3, cc + 3);
        lds_barrier();
    }
#undef A_LOAD
#undef A_STAGE
#undef A_COMPUTE

    // ---- ssq reduce + softmax over 64 k per p (R13 verbatim) ----
    *(f32x4*)&ssq_s[r][4 * q] = ssqv;
    __syncthreads();
    if (tid < 128) {
        float s = 0.f;
#pragma unroll
        for (int rr = 0; rr < 16; ++rr) s += ssq_s[rr][tid];
        ssq_l[tid] = s;
    }
    __syncthreads();
    float ssq = ssq_l[32 * ps + cl];
    float sinv = 1.0f / fmaxf(sqrtf(ssq), EPSN);
    float twoAs = 2.0f * ALPHA * sinv;
    float e[16];
    float m = -INFINITY;
#pragma unroll
    for (int rr = 0; rr < 16; ++rr) {
        int k = (rr & 3) + 8 * (rr >> 2) + 4 * h + 32 * kh;
        float lv = fmaf(twoAs, accA[rr] + accB[rr], bias_l[k]);
        e[rr] = lv;
        m = fmaxf(m, lv);
    }
    m = fmaxf(m, __shfl_xor(m, 32, 64));
    if (l < 32) xchm[ps][kh][l] = m;
    __syncthreads();
    m = fmaxf(m, xchm[ps][1 - kh][cl]);
    float ssum = 0.f;
#pragma unroll
    for (int rr = 0; rr < 16; ++rr) {
        e[rr] = expf(e[rr] - m);
        ssum += e[rr];
    }
    ssum += __shfl_xor(ssum, 32, 64);
    if (l < 32) xchs[ps][kh][l] = ssum;
    __syncthreads();
    ssum += xchs[ps][1 - kh][cl];
    float rs = 1.0f / ssum;
    float a2s = rs * sinv;
    // a2 -> LDS (replaces aT global store); asum atomic kept.
#pragma unroll
    for (int rr = 0; rr < 16; ++rr) {
        int k = (rr & 3) + 8 * (rr >> 2) + 4 * h + 32 * kh;
        a2f[k * 132 + 32 * ps + cl] = e[rr] * a2s;
        float red = e[rr] * rs;
#pragma unroll
        for (int off = 1; off <= 16; off <<= 1) red += __shfl_xor(red, off, 64);
        if (cl == 0) atomicAdd(&asum[n * 64 + k], red);
    }
    __syncthreads();

    // ---- vlad phase: D[k][c] partial over this block's 128 p ----
    // waves re-role: (kh, cq=ps). 4 rounds; round r2 stages c-subs
    // {128*cq + 32*r2 .. +31} for all cq (128 c rows), all 128 p, bf16-pairs.
    f32x16 va0, va1, va2, va3;
#pragma unroll
    for (int i = 0; i < 16; ++i) { va0[i] = 0.f; va1[i] = 0.f; va2[i] = 0.f; va3[i] = 0.f; }

    int g = tid >> 2, u = tid & 3;  // stage: c-row g (0..127), p-oct u
#pragma unroll
    for (int r2 = 0; r2 < 4; ++r2) {
        __syncthreads();  // previous round's reads done before overwrite
        {
            int c = (g >> 5) * 128 + r2 * 32 + (g & 31);
            const float* xs2 = x + (size_t)n * 524288 + (size_t)c * 1024 + pblk + 32 * u;
            float4 f0 = *(const float4*)(xs2);
            float4 f1 = *(const float4*)(xs2 + 4);
            float4 f2 = *(const float4*)(xs2 + 8);
            float4 f3 = *(const float4*)(xs2 + 12);
            float4 f4 = *(const float4*)(xs2 + 16);
            float4 f5 = *(const float4*)(xs2 + 20);
            float4 f6 = *(const float4*)(xs2 + 24);
            float4 f7 = *(const float4*)(xs2 + 28);
            u32x4 w0, w1, w2, w3;
            w0[0] = packbf(f0.x, f0.y); w0[1] = packbf(f0.z, f0.w);
            w0[2] = packbf(f1.x, f1.y); w0[3] = packbf(f1.z, f1.w);
            w1[0] = packbf(f2.x, f2.y); w1[1] = packbf(f2.z, f2.w);
            w1[2] = packbf(f3.x, f3.y); w1[3] = packbf(f3.z, f3.w);
            w2[0] = packbf(f4.x, f4.y); w2[1] = packbf(f4.z, f4.w);
            w2[2] = packbf(f5.x, f5.y); w2[3] = packbf(f5.z, f5.w);
            w3[0] = packbf(f6.x, f6.y); w3[1] = packbf(f6.z, f6.w);
            w3[2] = packbf(f7.x, f7.y); w3[3] = packbf(f7.z, f7.w);
            int xb0 = g * 68 + 16 * u;
            *(u32x4*)&xv[xb0] = w0;
            *(u32x4*)&xv[xb0 + 4] = w1;
            *(u32x4*)&xv[xb0 + 8] = w2;
            *(u32x4*)&xv[xb0 + 12] = w3;
        }
        __syncthreads();
        f32x16& vac = (r2 == 0) ? va0 : (r2 == 1) ? va1 : (r2 == 2) ? va2 : va3;
#pragma unroll
        for (int mm = 0; mm < 8; ++mm) {
            // A = a2 rows k (lane cl -> k=32kh+cl), K = p 16mm.. ; 8h half
            int ab = (32 * kh + cl) * 132 + 16 * mm + 8 * h;
            u32x4 af;
#pragma unroll
            for (int j = 0; j < 4; ++j)
                af[j] = packbf(a2f[ab + 2 * j], a2f[ab + 2 * j + 1]);
            int bb = (32 * ps + cl) * 68 + 8 * mm + 4 * h;
            u32x4 bf = *(const u32x4*)&xv[bb];
            vac = __builtin_amdgcn_mfma_f32_32x32x16_bf16(
                __builtin_bit_cast(bf16x8, af), __builtin_bit_cast(bf16x8, bf),
                vac, 0, 0, 0);
        }
    }
    // ---- store partials: pw[((n*8+pt)*64+k)*512 + c] ----
    float* pwb = pw + (((size_t)n * 8 + pt) * 64) * 512;
#pragma unroll
    for (int r2 = 0; r2 < 4; ++r2) {
        f32x16& vac = (r2 == 0) ? va0 : (r2 == 1) ? va1 : (r2 == 2) ? va2 : va3;
        int c = 128 * ps + 32 * r2 + cl;
#pragma unroll
        for (int rr = 0; rr < 16; ++rr) {
            int k = (rr & 3) + 8 * (rr >> 2) + 4 * h + 32 * kh;
            pwb[(size_t)k * 512 + c] = vac[rr];
        }
    }
}

// ====== combine: sum 8 p-partials, -asum*v, intra+global norms, write ======
// grid 32 = n; block 512.
__global__ __launch_bounds__(512) void combine_kernel(
    const float* __restrict__ pw, const float* __restrict__ asum,
    const float* __restrict__ vocabs, float* __restrict__ out) {
    __shared__ float lv[32768];  // val[k][c], 128 KB
    __shared__ float knorm_l[64];
    __shared__ float sc[64];
    __shared__ float tots;

    int n = blockIdx.x, tid = threadIdx.x;
    int kq = tid >> 7, tc = tid & 127;  // k-quarter, c-quad index
    const float* pwn = pw + (size_t)n * 262144;

    // phase 1: val = sum_pt pw - asum*v  -> LDS
#pragma unroll
    for (int ki = 0; ki < 16; ++ki) {
        int k = kq * 16 + ki;
        float a = asum[n * 64 + k];
        float4 vv = *(const float4*)(vocabs + (size_t)k * 512 + 4 * tc);
        float4 s = make_float4(0.f, 0.f, 0.f, 0.f);
#pragma unroll
        for (int pt = 0; pt < 8; ++pt) {
            float4 p4 = *(const float4*)(pwn + (size_t)pt * 32768 + (size_t)k * 512 + 4 * tc);
            s.x += p4.x; s.y += p4.y; s.z += p4.z; s.w += p4.w;
        }
        s.x = fmaf(-a, vv.x, s.x);
        s.y = fmaf(-a, vv.y, s.y);
        s.z = fmaf(-a, vv.z, s.z);
        s.w = fmaf(-a, vv.w, s.w);
        *(float4*)&lv[k * 512 + 4 * tc] = s;
    }
    __syncthreads();
    // phase 2: knorm[k] = sum_c val^2 (8 threads per k, shuffle-combine)
    {
        int k2 = tid >> 3, j = tid & 7;
        float t2 = 0.f;
#pragma unroll
        for (int i = 0; i < 16; ++i) {
            float4 v4 = *(const float4*)&lv[k2 * 512 + j * 64 + 4 * i];
            t2 += v4.x * v4.x + v4.y * v4.y + v4.z * v4.z + v4.w * v4.w;
        }
        t2 += __shfl_xor(t2, 1, 64);
        t2 += __shfl_xor(t2, 2, 64);
        t2 += __shfl_xor(t2, 4, 64);
        if (j == 0) knorm_l[k2] = t2;
    }
    __syncthreads();
    // phase 3: per-k scale + total norm (wave 0)
    if (tid < 64) {
        float nk = sqrtf(knorm_l[tid]);
        float inv = 1.0f / fmaxf(nk, EPSN);
        sc[tid] = inv;
        float t = nk * inv;
        float t2 = t * t;
#pragma unroll
        for (int off = 32; off > 0; off >>= 1) t2 += __shfl_xor(t2, off, 64);
        if (tid == 0) tots = t2;
    }
    __syncthreads();
    // phase 4: scale + write
    float invt = 1.0f / fmaxf(sqrtf(tots), EPSN);
    float* on = out + (size_t)n * 32768;
#pragma unroll
    for (int i = 0; i < 64; ++i) {
        int idx = tid + 512 * i;
        on[idx] = lv[idx] * sc[idx >> 9] * invt;
    }
}

extern "C" void kernel_launch(void* const* d_in, const int* in_sizes, int n_in,
                              void* d_out, int out_size, void* d_ws, size_t ws_size,
                              hipStream_t stream) {
    const float* x = (const float*)d_in[0];       // [32,512,32,32]
    const float* vocabs = (const float*)d_in[1];  // [64,512]
    float* out = (float*)d_out;                   // [32, 32768]
    char* ws = (char*)d_ws;
    unsigned short* vh = (unsigned short*)(ws);            // 65536 B
    unsigned short* vl = (unsigned short*)(ws + 65536);    // 65536 B
    float* bias  = (float*)(ws + 131072);                  //   256 B
    float* asum  = (float*)(ws + 131328);                  //  8192 B
    float* pw    = (float*)(ws + 147712);                  // 32 MB partials

    prep_kernel<<<64, 64, 0, stream>>>(vocabs, vh, vl, bias, asum);
    fused_kernel<<<256, 512, 0, stream>>>(x, vh, vl, bias, pw, asum);
    combine_kernel<<<32, 512, 0, stream>>>(pw, asum, vocabs, out);
}